// Round 1
// baseline (175.640 us; speedup 1.0000x reference)
//
#include <hip/hip_runtime.h>
#include <hip/hip_bf16.h>

// Shapes (fixed by the reference)
#define BB 16
#define HH 64
#define WW 64
#define CC 256
#define OH 128
#define OW 128
#define FF 256

typedef __attribute__((ext_vector_type(8))) short bf16x8;
typedef __attribute__((ext_vector_type(4))) float f32x4;

// RNE float -> bf16 bits
__device__ __forceinline__ short f2bf(float x) {
    union { float f; unsigned u; } v; v.f = x;
    unsigned r = v.u + 0x7fffu + ((v.u >> 16) & 1u);
    return (short)(r >> 16);
}

// Transpose pw [c][f] (f32) -> pwt [f][c] (bf16). 256x256, tiny.
__global__ void prep_pwt_kernel(const float* __restrict__ pw, short* __restrict__ pwt) {
    int f = blockIdx.x;
    int c = threadIdx.x;
    pwt[f * CC + c] = f2bf(pw[c * FF + f]);
}

__device__ __forceinline__ void tap(float acc[8], const float w[8], const float* xptr) {
    const float4* xp = reinterpret_cast<const float4*>(xptr);
    float4 x0 = xp[0], x1 = xp[1];
    acc[0] += w[0] * x0.x; acc[1] += w[1] * x0.y;
    acc[2] += w[2] * x0.z; acc[3] += w[3] * x0.w;
    acc[4] += w[4] * x1.x; acc[5] += w[5] * x1.y;
    acc[6] += w[6] * x1.z; acc[7] += w[7] * x1.w;
}

__global__ __launch_bounds__(512, 4)
void sepconvt_kernel(const float* __restrict__ X,
                     const float* __restrict__ dw,
                     const short* __restrict__ pwt,
                     const float* __restrict__ bias,
                     float* __restrict__ out) {
    __shared__ float dw_lds[2][4][CC];            // 8 KiB: the 2 needed kernel rows
    __shared__ bf16x8 t_lds[OW * (CC / 8)];       // 64 KiB: depthwise result, swizzled

    const int tid = threadIdx.x;
    const int blk = blockIdx.x;
    const int oh = blk & (OH - 1);
    const int b  = blk >> 7;

    // Row taps: even oh -> (r=1, i=oh/2), (r=3, i=oh/2-1); odd -> (r=0,(oh+1)/2),(r=2,(oh-1)/2)
    int r0, r1, i0, i1;
    if (oh & 1) { r0 = 0; i0 = (oh + 1) >> 1; r1 = 2; i1 = (oh - 1) >> 1; }
    else        { r0 = 1; i0 = oh >> 1;       r1 = 3; i1 = (oh >> 1) - 1; }

    // Stage dw rows r0, r1 (all s, all c) into LDS: dw[(r*4+s)*256 + c]
    for (int k = tid; k < 2 * 4 * CC; k += 512) {
        int a = k >> 10;            // 0/1
        int rem = k & 1023;         // s*256 + c
        int r = a ? r1 : r0;
        ((float*)dw_lds)[k] = dw[r * 1024 + rem];
    }
    __syncthreads();

    // ---- Phase 1: depthwise transposed conv -> t_lds (bf16) ----
    {
        const int cg  = tid & 31;      // 8-channel group
        const int c0  = cg << 3;
        const int owp = tid >> 5;      // 0..15, parity fixed per thread
        const int parity = owp & 1;
        const int se = parity ? 0 : 1;
        const int so = parity ? 2 : 3;

        float w[2][2][8];
        #pragma unroll
        for (int a = 0; a < 2; ++a)
            #pragma unroll
            for (int e = 0; e < 8; ++e) {
                w[a][0][e] = dw_lds[a][se][c0 + e];
                w[a][1][e] = dw_lds[a][so][c0 + e];
            }

        const bool va0 = (unsigned)i0 < HH;
        const bool va1 = (unsigned)i1 < HH;
        const float* Xr0 = X + (size_t)(b * HH + (va0 ? i0 : 0)) * WW * CC;
        const float* Xr1 = X + (size_t)(b * HH + (va1 ? i1 : 0)) * WW * CC;

        for (int ow = owp; ow < OW; ow += 16) {
            int je, jo;
            if (parity) { je = (ow + 1) >> 1; jo = (ow - 1) >> 1; }
            else        { je = ow >> 1;       jo = (ow >> 1) - 1; }
            const bool vje = (unsigned)je < WW;
            const bool vjo = (unsigned)jo < WW;

            float acc[8];
            #pragma unroll
            for (int e = 0; e < 8; ++e) acc[e] = 0.f;

            if (va0) {
                if (vje) tap(acc, w[0][0], Xr0 + je * CC + c0);
                if (vjo) tap(acc, w[0][1], Xr0 + jo * CC + c0);
            }
            if (va1) {
                if (vje) tap(acc, w[1][0], Xr1 + je * CC + c0);
                if (vjo) tap(acc, w[1][1], Xr1 + jo * CC + c0);
            }

            bf16x8 tv;
            #pragma unroll
            for (int e = 0; e < 8; ++e) tv[e] = f2bf(acc[e]);
            t_lds[ow * 32 + (cg ^ (ow & 7))] = tv;
        }
    }
    __syncthreads();

    // ---- Phase 2: pointwise GEMM via MFMA ----
    const int lane = tid & 63;
    const int wid  = tid >> 6;       // 8 waves: 2 (M) x 4 (N)
    const int wr = wid >> 2;
    const int wc = wid & 3;
    const int lr  = lane & 15;
    const int lk8 = lane >> 4;       // k-subgroup 0..3

    f32x4 acc[4][4];
    #pragma unroll
    for (int mi = 0; mi < 4; ++mi)
        #pragma unroll
        for (int ni = 0; ni < 4; ++ni)
            acc[mi][ni] = (f32x4){0.f, 0.f, 0.f, 0.f};

    const bf16x8* pwt_v = reinterpret_cast<const bf16x8*>(pwt);

    for (int kk = 0; kk < 8; ++kk) {            // K = 256, 32 per mfma
        const int kg = kk * 4 + lk8;            // 16B group index along K
        bf16x8 af[4], bfr[4];
        #pragma unroll
        for (int mi = 0; mi < 4; ++mi) {
            int ow = wr * 64 + mi * 16 + lr;
            af[mi] = t_lds[ow * 32 + (kg ^ (ow & 7))];
        }
        #pragma unroll
        for (int ni = 0; ni < 4; ++ni) {
            int n = wc * 64 + ni * 16 + lr;
            bfr[ni] = pwt_v[n * 32 + kg];
        }
        #pragma unroll
        for (int mi = 0; mi < 4; ++mi)
            #pragma unroll
            for (int ni = 0; ni < 4; ++ni)
                acc[mi][ni] = __builtin_amdgcn_mfma_f32_16x16x32_bf16(
                    af[mi], bfr[ni], acc[mi][ni], 0, 0, 0);
    }

    // ---- Epilogue: bias + relu + store ----
    float* orow = out + (size_t)(b * OH + oh) * OW * FF;
    const int q0 = lk8 * 4;
    #pragma unroll
    for (int ni = 0; ni < 4; ++ni) {
        int f = wc * 64 + ni * 16 + lr;
        float bv = bias[f];
        #pragma unroll
        for (int mi = 0; mi < 4; ++mi) {
            int m = wr * 64 + mi * 16 + q0;
            #pragma unroll
            for (int q = 0; q < 4; ++q) {
                float v = acc[mi][ni][q] + bv;
                orow[(size_t)(m + q) * FF + f] = v > 0.f ? v : 0.f;
            }
        }
    }
}

extern "C" void kernel_launch(void* const* d_in, const int* in_sizes, int n_in,
                              void* d_out, int out_size, void* d_ws, size_t ws_size,
                              hipStream_t stream) {
    (void)in_sizes; (void)n_in; (void)out_size; (void)ws_size;
    const float* X    = (const float*)d_in[0];
    const float* dw   = (const float*)d_in[1];
    const float* pw   = (const float*)d_in[2];
    const float* bias = (const float*)d_in[3];
    float* out = (float*)d_out;
    short* pwt = (short*)d_ws;   // 256*256*2 = 128 KiB scratch

    prep_pwt_kernel<<<dim3(FF), dim3(CC), 0, stream>>>(pw, pwt);
    sepconvt_kernel<<<dim3(BB * OH), dim3(512), 0, stream>>>(X, dw, pwt, bias, out);
}